// Round 1
// baseline (2587.717 us; speedup 1.0000x reference)
//
#include <hip/hip_runtime.h>
#include <stdint.h>

#define D_IN 2048
#define HID  16384
#define NTOK 8192
#define KSEL 64
#define CANDCAP 512
#define MARGIN 0.05f

typedef __attribute__((ext_vector_type(8))) short bf16x8;
typedef __attribute__((ext_vector_type(4))) float f32x4;
typedef unsigned int u32;
typedef unsigned short u16;

__device__ __forceinline__ u16 f2bf(float f){
  u32 b = __builtin_bit_cast(u32, f);
  return (u16)((b + 0x7FFFu + ((b>>16)&1u)) >> 16);
}
__device__ __forceinline__ u16 key_of_bf(u16 u){
  return (u & 0x8000u) ? (u16)(~u) : (u16)(u | 0x8000u);
}
__device__ __forceinline__ u32 fkey(float f){ return (u32)key_of_bf(f2bf(f)); }
__device__ __forceinline__ u32 key2(u32 p){
  u32 lo = p & 0xFFFFu, hi = p >> 16;
  lo = (lo & 0x8000u) ? ((~lo)&0xFFFFu) : (lo|0x8000u);
  hi = (hi & 0x8000u) ? ((~hi)&0xFFFFu) : (hi|0x8000u);
  return lo | (hi<<16);
}

// ---------------- convert: x-mean -> bf16, enc_w -> bf16 ----------------
__global__ __launch_bounds__(256) void k_convert_x(const float* __restrict__ x,
                                                   const float* __restrict__ mean,
                                                   u16* __restrict__ xb){
  long i = (long)blockIdx.x*256 + threadIdx.x;  // 8 elems each
  long base = i*8;
  int d = (int)(base & (D_IN-1));
  float4 a = *(const float4*)(x+base);
  float4 b = *(const float4*)(x+base+4);
  float4 m0 = *(const float4*)(mean+d);
  float4 m1 = *(const float4*)(mean+d+4);
  uint4 ov;
  ov.x = (u32)f2bf(a.x-m0.x) | ((u32)f2bf(a.y-m0.y)<<16);
  ov.y = (u32)f2bf(a.z-m0.z) | ((u32)f2bf(a.w-m0.w)<<16);
  ov.z = (u32)f2bf(b.x-m1.x) | ((u32)f2bf(b.y-m1.y)<<16);
  ov.w = (u32)f2bf(b.z-m1.z) | ((u32)f2bf(b.w-m1.w)<<16);
  *(uint4*)(xb+base) = ov;
}

__global__ __launch_bounds__(256) void k_convert_w(const float* __restrict__ wsrc,
                                                   u16* __restrict__ wb){
  long i = (long)blockIdx.x*256 + threadIdx.x;
  long base = i*8;
  float4 a = *(const float4*)(wsrc+base);
  float4 b = *(const float4*)(wsrc+base+4);
  uint4 ov;
  ov.x = (u32)f2bf(a.x) | ((u32)f2bf(a.y)<<16);
  ov.y = (u32)f2bf(a.z) | ((u32)f2bf(a.w)<<16);
  ov.z = (u32)f2bf(b.x) | ((u32)f2bf(b.y)<<16);
  ov.w = (u32)f2bf(b.z) | ((u32)f2bf(b.w)<<16);
  *(uint4*)(wb+base) = ov;
}

// ---------------- bf16 GEMM: z = (x-mean) @ enc_w^T + enc_b  (m97-style 128x128, BK=64) ----
__global__ __launch_bounds__(256) void k_gemm(const u16* __restrict__ A,   // [NTOK, D_IN] bf16
                                              const u16* __restrict__ B,   // [HID, D_IN] bf16
                                              const float* __restrict__ bias,
                                              u16* __restrict__ Z){        // [NTOK, HID] bf16
  __shared__ u16 As[128*64];
  __shared__ u16 Bs[128*64];
  int t = threadIdx.x, lane = t & 63, w = t >> 6;
  int wm = w >> 1, wn = w & 1;
  // XCD-aware bijective swizzle (nwg=8192 divisible by 8), bn-major panels
  int wg = blockIdx.x;
  int swz = (wg & 7)*1024 + (wg >> 3);
  int bn = swz >> 6;     // 0..127
  int bm = swz & 63;     // 0..63
  const u16* aBase = A + (size_t)bm*128*D_IN;
  const u16* bBase = B + (size_t)bn*128*D_IN;
  int r = t >> 3;        // staging row 0..31
  int c = t & 7;         // staging 16B chunk 0..7
  int l15 = lane & 15, lhi = lane >> 4, l7 = lane & 7;
  f32x4 acc[4][4] = {};
  for (int kt = 0; kt < D_IN/64; ++kt){
    __syncthreads();
    #pragma unroll
    for (int i = 0; i < 4; ++i){
      int rr = r + 32*i;
      int cs = c ^ (rr & 7);   // pre-swizzled global source, linear LDS dest
      __builtin_amdgcn_global_load_lds(
        (const __attribute__((address_space(1))) u32*)(aBase + (size_t)rr*D_IN + kt*64 + cs*8),
        (__attribute__((address_space(3))) u32*)(As + t*8 + i*2048), 16, 0, 0);
    }
    #pragma unroll
    for (int i = 0; i < 4; ++i){
      int rr = r + 32*i;
      int cs = c ^ (rr & 7);
      __builtin_amdgcn_global_load_lds(
        (const __attribute__((address_space(1))) u32*)(bBase + (size_t)rr*D_IN + kt*64 + cs*8),
        (__attribute__((address_space(3))) u32*)(Bs + t*8 + i*2048), 16, 0, 0);
    }
    __syncthreads();
    #pragma unroll
    for (int kk = 0; kk < 2; ++kk){
      int kc = kk*4 + lhi;
      int sw = ((kc ^ l7) << 3);  // swizzled read matches swizzled store
      bf16x8 af[4], bg[4];
      #pragma unroll
      for (int fm = 0; fm < 4; ++fm)
        af[fm] = *(const bf16x8*)(As + (wm*64 + fm*16 + l15)*64 + sw);
      #pragma unroll
      for (int fn = 0; fn < 4; ++fn)
        bg[fn] = *(const bf16x8*)(Bs + (wn*64 + fn*16 + l15)*64 + sw);
      #pragma unroll
      for (int fm = 0; fm < 4; ++fm)
        #pragma unroll
        for (int fn = 0; fn < 4; ++fn)
          acc[fm][fn] = __builtin_amdgcn_mfma_f32_16x16x32_bf16(af[fm], bg[fn], acc[fm][fn], 0, 0, 0);
    }
  }
  // epilogue: C/D layout col=lane&15, row=(lane>>4)*4+j  (m89-verified)
  #pragma unroll
  for (int fn = 0; fn < 4; ++fn){
    int gc = bn*128 + wn*64 + fn*16 + l15;
    float bv = bias[gc];
    #pragma unroll
    for (int fm = 0; fm < 4; ++fm){
      size_t grow = (size_t)bm*128 + wm*64 + fm*16 + lhi*4;
      #pragma unroll
      for (int j = 0; j < 4; ++j)
        Z[(grow + j)*HID + gc] = f2bf(acc[fm][fn][j] + bv);
    }
  }
}

// ---------------- top-k candidate selection (binary search on threshold) ----------------
__global__ __launch_bounds__(256) void k_topk(const u16* __restrict__ Z,
                                              int* __restrict__ cand,
                                              int* __restrict__ cnt_out){
  __shared__ uint4 k4[2048];   // 16384 order-keys (u16), 32KB
  __shared__ int part[4];
  __shared__ int s_cnt;
  int row = blockIdx.x, t = threadIdx.x, lane = t & 63, w = t >> 6;
  const uint4* zr = (const uint4*)(Z + (size_t)row*HID);
  #pragma unroll
  for (int j = 0; j < 8; ++j){
    int ci = t + 256*j;
    uint4 v = zr[ci];
    uint4 kk; kk.x = key2(v.x); kk.y = key2(v.y); kk.z = key2(v.z); kk.w = key2(v.w);
    k4[ci] = kk;
  }
  if (t == 0) s_cnt = 0;
  __syncthreads();
  float lo = -16.f, hi = 16.f;
  for (int it = 0; it < 20; ++it){
    float mid = 0.5f*(lo+hi);
    u32 kt = fkey(mid);
    int cnt = 0;
    #pragma unroll
    for (int j = 0; j < 8; ++j){
      uint4 v = k4[t + 256*j];
      cnt += ((v.x & 0xFFFFu) >= kt) + ((v.x>>16) >= kt)
           + ((v.y & 0xFFFFu) >= kt) + ((v.y>>16) >= kt)
           + ((v.z & 0xFFFFu) >= kt) + ((v.z>>16) >= kt)
           + ((v.w & 0xFFFFu) >= kt) + ((v.w>>16) >= kt);
    }
    #pragma unroll
    for (int off = 32; off; off >>= 1) cnt += __shfl_down(cnt, off);
    if (lane == 0) part[w] = cnt;
    __syncthreads();
    int tot = part[0] + part[1] + part[2] + part[3];
    if (tot >= KSEL) lo = mid; else hi = mid;
    __syncthreads();
  }
  u32 ktc = fkey(lo - MARGIN);
  #pragma unroll
  for (int j = 0; j < 8; ++j){
    int ci = t + 256*j;
    uint4 v = k4[ci];
    u32 hw[8] = { v.x & 0xFFFFu, v.x>>16, v.y & 0xFFFFu, v.y>>16,
                  v.z & 0xFFFFu, v.z>>16, v.w & 0xFFFFu, v.w>>16 };
    #pragma unroll
    for (int e = 0; e < 8; ++e){
      if (hw[e] >= ktc){
        int pos = atomicAdd(&s_cnt, 1);
        if (pos < CANDCAP) cand[(size_t)row*CANDCAP + pos] = ci*8 + e;
      }
    }
  }
  __syncthreads();
  if (t == 0) cnt_out[row] = s_cnt < CANDCAP ? s_cnt : CANDCAP;
}

// ---------------- fp64 refinement + exact top-64 ----------------
__global__ __launch_bounds__(256) void k_refine(const float* __restrict__ x,
                                                const float* __restrict__ mean,
                                                const float* __restrict__ encw,
                                                const float* __restrict__ encb,
                                                const int* __restrict__ cand,
                                                const int* __restrict__ cnt_in,
                                                int* __restrict__ tki,
                                                float* __restrict__ tkv){
  __shared__ float xc[D_IN];       // 8KB centered row
  __shared__ double vals[CANDCAP]; // 4KB
  __shared__ int idxs[CANDCAP];    // 2KB
  int row = blockIdx.x, t = threadIdx.x, lane = t & 63, w = t >> 6;
  const float* xr = x + (size_t)row*D_IN;
  for (int i = t; i < D_IN; i += 256) xc[i] = xr[i] - mean[i];
  int cnt = cnt_in[row];
  for (int i = t; i < cnt; i += 256) idxs[i] = cand[(size_t)row*CANDCAP + i];
  __syncthreads();
  for (int cidx = w; cidx < cnt; cidx += 4){
    int h = idxs[cidx];
    const float* wr = encw + (size_t)h*D_IN;
    double s = 0.0;
    #pragma unroll 8
    for (int e = 0; e < 32; ++e){
      int d = lane + 64*e;
      s = fma((double)xc[d], (double)wr[d], s);
    }
    #pragma unroll
    for (int off = 32; off; off >>= 1) s += __shfl_down(s, off);
    if (lane == 0) vals[cidx] = s + (double)encb[h];
  }
  __syncthreads();
  for (int i = t; i < cnt; i += 256){
    double v = vals[i]; int h = idxs[i];
    int rank = 0;
    for (int j = 0; j < cnt; ++j){
      double vj = vals[j];
      rank += (vj > v) || (vj == v && idxs[j] < h);
    }
    if (rank < KSEL){ tki[(size_t)row*KSEL + rank] = h; tkv[(size_t)row*KSEL + rank] = (float)v; }
  }
}

// ---------------- dec_w transpose [2048,16384] -> [16384,2048] ----------------
__global__ __launch_bounds__(256) void k_transpose(const float* __restrict__ src,
                                                   float* __restrict__ dst){
  __shared__ float tile[32][33];
  int tx = threadIdx.x & 31, ty = threadIdx.x >> 5;  // ty 0..7
  int bh = blockIdx.x;  // 0..511 (h tiles)
  int bd = blockIdx.y;  // 0..63  (d tiles)
  #pragma unroll
  for (int i = 0; i < 4; ++i){
    int d = bd*32 + ty + i*8;
    tile[ty + i*8][tx] = src[(size_t)d*HID + bh*32 + tx];
  }
  __syncthreads();
  #pragma unroll
  for (int i = 0; i < 4; ++i){
    int h = bh*32 + ty + i*8;
    dst[(size_t)h*D_IN + bd*32 + tx] = tile[tx][ty + i*8];
  }
}

// ---------------- sparse decode: out = sum_k v_k * dec_wT[h_k,:] + dec_b + mean ----------------
__global__ __launch_bounds__(256) void k_decode(const float* __restrict__ wT,
                                                const int* __restrict__ tki,
                                                const float* __restrict__ tkv,
                                                const float* __restrict__ decb,
                                                const float* __restrict__ mean,
                                                float* __restrict__ out){
  __shared__ int hk[KSEL];
  __shared__ float vk[KSEL];
  int n = blockIdx.x, t = threadIdx.x;
  if (t < KSEL){ hk[t] = tki[(size_t)n*KSEL + t]; vk[t] = tkv[(size_t)n*KSEL + t]; }
  __syncthreads();
  int d0 = t*8;
  float4 a0 = {0,0,0,0}, a1 = {0,0,0,0};
  for (int k = 0; k < KSEL; ++k){
    const float* wr = wT + (size_t)hk[k]*D_IN + d0;
    float v = vk[k];
    float4 w0 = *(const float4*)wr;
    float4 w1 = *(const float4*)(wr+4);
    a0.x = fmaf(v, w0.x, a0.x); a0.y = fmaf(v, w0.y, a0.y);
    a0.z = fmaf(v, w0.z, a0.z); a0.w = fmaf(v, w0.w, a0.w);
    a1.x = fmaf(v, w1.x, a1.x); a1.y = fmaf(v, w1.y, a1.y);
    a1.z = fmaf(v, w1.z, a1.z); a1.w = fmaf(v, w1.w, a1.w);
  }
  float4 b0 = *(const float4*)(decb+d0);
  float4 b1 = *(const float4*)(decb+d0+4);
  float4 m0 = *(const float4*)(mean+d0);
  float4 m1 = *(const float4*)(mean+d0+4);
  float4 o0 = { a0.x+b0.x+m0.x, a0.y+b0.y+m0.y, a0.z+b0.z+m0.z, a0.w+b0.w+m0.w };
  float4 o1 = { a1.x+b1.x+m1.x, a1.y+b1.y+m1.y, a1.z+b1.z+m1.z, a1.w+b1.w+m1.w };
  *(float4*)(out + (size_t)n*D_IN + d0)     = o0;
  *(float4*)(out + (size_t)n*D_IN + d0 + 4) = o1;
}

// ---------------- workspace layout (bytes) ----------------
#define OFF_XB   ((size_t)0)                       // 33,554,432  x bf16
#define OFF_WB   ((size_t)33554432)                // 67,108,864  enc_w bf16
#define OFF_CAND ((size_t)100663296)               // 16,777,216  cand idx
#define OFF_CCNT ((size_t)117440512)               // 32,768
#define OFF_TKI  ((size_t)117473280)               // 2,097,152
#define OFF_TKV  ((size_t)119570432)               // 2,097,152
#define OFF_Z    ((size_t)121667584)               // 268,435,456 z bf16
#define OFF_WT   OFF_Z                             // 134,217,728 dec_wT (reuses z after topk)
// total required: 390,103,040 bytes (~372 MB)

extern "C" void kernel_launch(void* const* d_in, const int* in_sizes, int n_in,
                              void* d_out, int out_size, void* d_ws, size_t ws_size,
                              hipStream_t stream) {
  const float* x     = (const float*)d_in[0];
  const float* enc_w = (const float*)d_in[1];
  const float* enc_b = (const float*)d_in[2];
  const float* dec_w = (const float*)d_in[3];
  const float* dec_b = (const float*)d_in[4];
  const float* mean  = (const float*)d_in[5];
  float* out = (float*)d_out;
  char* ws = (char*)d_ws;

  u16* xb   = (u16*)(ws + OFF_XB);
  u16* wb   = (u16*)(ws + OFF_WB);
  int* cand = (int*)(ws + OFF_CAND);
  int* ccnt = (int*)(ws + OFF_CCNT);
  int* tki  = (int*)(ws + OFF_TKI);
  float* tkv = (float*)(ws + OFF_TKV);
  u16* z    = (u16*)(ws + OFF_Z);
  float* wT = (float*)(ws + OFF_WT);

  k_convert_x<<<NTOK*D_IN/8/256, 256, 0, stream>>>(x, mean, xb);
  k_convert_w<<<(size_t)HID*D_IN/8/256, 256, 0, stream>>>(enc_w, wb);
  k_gemm<<<(NTOK/128)*(HID/128), 256, 0, stream>>>(xb, wb, enc_b, z);
  k_topk<<<NTOK, 256, 0, stream>>>(z, cand, ccnt);
  k_refine<<<NTOK, 256, 0, stream>>>(x, mean, enc_w, enc_b, cand, ccnt, tki, tkv);
  k_transpose<<<dim3(HID/32, D_IN/32), 256, 0, stream>>>(dec_w, wT);
  k_decode<<<NTOK, 256, 0, stream>>>(wT, tki, tkv, dec_b, mean, out);
}

// Round 2
// 1802.434 us; speedup vs baseline: 1.4357x; 1.4357x over previous
//
#include <hip/hip_runtime.h>
#include <stdint.h>

#define D_IN 2048
#define HID  16384
#define NTOK 8192
#define KSEL 64
#define CANDCAP 512
#define MARGIN 0.05f

typedef __attribute__((ext_vector_type(8))) short bf16x8;
typedef __attribute__((ext_vector_type(4))) float f32x4;
typedef unsigned int u32;
typedef unsigned short u16;

__device__ __forceinline__ u16 f2bf(float f){
  u32 b = __builtin_bit_cast(u32, f);
  return (u16)((b + 0x7FFFu + ((b>>16)&1u)) >> 16);
}
__device__ __forceinline__ float bf2f(u16 u){
  return __builtin_bit_cast(float, (u32)u << 16);
}
__device__ __forceinline__ u16 key_of_bf(u16 u){
  return (u & 0x8000u) ? (u16)(~u) : (u16)(u | 0x8000u);
}
__device__ __forceinline__ u32 fkey(float f){ return (u32)key_of_bf(f2bf(f)); }
__device__ __forceinline__ u32 key2(u32 p){
  u32 lo = p & 0xFFFFu, hi = p >> 16;
  lo = (lo & 0x8000u) ? ((~lo)&0xFFFFu) : (lo|0x8000u);
  hi = (hi & 0x8000u) ? ((~hi)&0xFFFFu) : (hi|0x8000u);
  return lo | (hi<<16);
}

// ---------------- convert: x-mean -> bf16, enc_w -> bf16 ----------------
__global__ __launch_bounds__(256) void k_convert_x(const float* __restrict__ x,
                                                   const float* __restrict__ mean,
                                                   u16* __restrict__ xb){
  long i = (long)blockIdx.x*256 + threadIdx.x;
  long base = i*8;
  int d = (int)(base & (D_IN-1));
  float4 a = *(const float4*)(x+base);
  float4 b = *(const float4*)(x+base+4);
  float4 m0 = *(const float4*)(mean+d);
  float4 m1 = *(const float4*)(mean+d+4);
  uint4 ov;
  ov.x = (u32)f2bf(a.x-m0.x) | ((u32)f2bf(a.y-m0.y)<<16);
  ov.y = (u32)f2bf(a.z-m0.z) | ((u32)f2bf(a.w-m0.w)<<16);
  ov.z = (u32)f2bf(b.x-m1.x) | ((u32)f2bf(b.y-m1.y)<<16);
  ov.w = (u32)f2bf(b.z-m1.z) | ((u32)f2bf(b.w-m1.w)<<16);
  *(uint4*)(xb+base) = ov;
}

__global__ __launch_bounds__(256) void k_convert_w(const float* __restrict__ wsrc,
                                                   u16* __restrict__ wb){
  long i = (long)blockIdx.x*256 + threadIdx.x;
  long base = i*8;
  float4 a = *(const float4*)(wsrc+base);
  float4 b = *(const float4*)(wsrc+base+4);
  uint4 ov;
  ov.x = (u32)f2bf(a.x) | ((u32)f2bf(a.y)<<16);
  ov.y = (u32)f2bf(a.z) | ((u32)f2bf(a.w)<<16);
  ov.z = (u32)f2bf(b.x) | ((u32)f2bf(b.y)<<16);
  ov.w = (u32)f2bf(b.z) | ((u32)f2bf(b.w)<<16);
  *(uint4*)(wb+base) = ov;
}

// ---------------- bf16 GEMM, 256x256 tile, BK=64, 8 waves, 8-phase counted-vmcnt ----------------
// LDS per buffer: A = 2 kh-halves of [256][32] bf16 (16KB each), B same. 2 buffers = 128KB.
// Swizzle: within a half, superrow sr = r>>1 (128B, 8 x 16B slots); slot = (((r&1)<<2)|c16) ^ (sr&7).
__global__ __launch_bounds__(512, 2) void k_gemm(const u16* __restrict__ A,   // [NTOK, D_IN]
                                                 const u16* __restrict__ B,   // [HID, D_IN]
                                                 const float* __restrict__ bias,
                                                 u16* __restrict__ Z){        // [NTOK, HID]
  __shared__ u16 lds[65536];   // 128 KiB
  const int t = threadIdx.x, lane = t & 63, w = t >> 6;
  const int wm = w >> 2, wn = w & 3;
  const int l15 = lane & 15, lhi = lane >> 4;

  // bijective XCD swizzle (2048 % 8 == 0) + 8x8 2D chunking
  int wg = blockIdx.x;
  int wgid = (wg & 7)*256 + (wg >> 3);
  int sb = wgid >> 6, wi = wgid & 63;
  int bm = (sb & 3)*8 + (wi & 7);      // 0..31
  int bn = (sb >> 2)*8 + (wi >> 3);    // 0..63
  const u16* aT = A + (size_t)bm*256*D_IN;
  const u16* bT = B + (size_t)bn*256*D_IN;

  // staging precompute: load-inst i covers LDS bytes [i*8192 + w*1024 + lane*16 .. +16)
  int srcOff[2], ldst[2];
  #pragma unroll
  for (int i = 0; i < 2; ++i){
    int sr = i*64 + w*8 + (lane >> 3);
    int u  = (lane & 7) ^ (sr & 7);
    int r  = (sr << 1) | (u >> 2);
    int c8 = (u & 3) * 8;
    srcOff[i] = r*D_IN + c8;               // + kt*64 + kh*32 at use
    ldst[i]   = i*4096 + w*512 + lane*8;   // u16 index within 8192-u16 half
  }
  #define STAGE(bufb, ktp, khh, isB) do { \
    const u16* _s = ((isB) ? bT : aT) + (ktp)*64 + (khh)*32; \
    u16* _d = lds + (bufb)*32768 + ((isB)?16384:0) + (khh)*8192; \
    __builtin_amdgcn_global_load_lds( \
      (const __attribute__((address_space(1))) u32*)(_s + srcOff[0]), \
      (__attribute__((address_space(3))) u32*)(_d + ldst[0]), 16, 0, 0); \
    __builtin_amdgcn_global_load_lds( \
      (const __attribute__((address_space(1))) u32*)(_s + srcOff[1]), \
      (__attribute__((address_space(3))) u32*)(_d + ldst[1]), 16, 0, 0); \
  } while(0)

  // ds_read lane offsets (u16 units). r&7-dependent parts are fm/fn/kh-invariant.
  const int slot = ((((l15 & 1) << 2) | lhi) ^ (l15 >> 1)) * 8;
  const int aoff = (wm*64 + (l15 >> 1))*64 + slot;   // + fm*512 + kh*8192 + buf*32768
  const int boff = (wn*32 + (l15 >> 1))*64 + slot + 16384;

  f32x4 acc[8][4] = {};

  // prologue: tile 0, all 4 halves into buf 0
  STAGE(0, 0, 0, 0); STAGE(0, 0, 0, 1); STAGE(0, 0, 1, 0); STAGE(0, 0, 1, 1);

  #pragma unroll 1
  for (int kt = 0; kt < D_IN/64; ++kt){
    const int cur = kt & 1, nxt = cur ^ 1;
    const int ab = cur*32768;
    const bool pre = (kt < D_IN/64 - 1);
    bf16x8 av[4], bv[4];

    // ---- phase 1: kh0, fm 0-3 (needs A-kh0 + B-kh0; 4 newer loads may fly) ----
    asm volatile("s_waitcnt vmcnt(4)" ::: "memory");
    __builtin_amdgcn_s_barrier();
    #pragma unroll
    for (int fm = 0; fm < 4; ++fm) av[fm] = *(const bf16x8*)(lds + ab + aoff + fm*512);
    #pragma unroll
    for (int fn = 0; fn < 4; ++fn) bv[fn] = *(const bf16x8*)(lds + ab + boff + fn*512);
    if (pre) STAGE(nxt, kt+1, 0, 0);
    __builtin_amdgcn_s_setprio(1);
    #pragma unroll
    for (int fm = 0; fm < 4; ++fm)
      #pragma unroll
      for (int fn = 0; fn < 4; ++fn)
        acc[fm][fn] = __builtin_amdgcn_mfma_f32_16x16x32_bf16(av[fm], bv[fn], acc[fm][fn], 0, 0, 0);
    __builtin_amdgcn_s_setprio(0);

    // ---- phase 2: kh0, fm 4-7 (B regs reused) ----
    #pragma unroll
    for (int fm = 0; fm < 4; ++fm) av[fm] = *(const bf16x8*)(lds + ab + aoff + (fm+4)*512);
    if (pre) STAGE(nxt, kt+1, 0, 1);
    __builtin_amdgcn_s_setprio(1);
    #pragma unroll
    for (int fm = 0; fm < 4; ++fm)
      #pragma unroll
      for (int fn = 0; fn < 4; ++fn)
        acc[fm+4][fn] = __builtin_amdgcn_mfma_f32_16x16x32_bf16(av[fm], bv[fn], acc[fm+4][fn], 0, 0, 0);
    __builtin_amdgcn_s_setprio(0);

    // ---- phase 3: kh1, fm 0-3 ----
    if (pre) { asm volatile("s_waitcnt vmcnt(4)" ::: "memory"); }
    else     { asm volatile("s_waitcnt vmcnt(0)" ::: "memory"); }
    __builtin_amdgcn_s_barrier();
    #pragma unroll
    for (int fm = 0; fm < 4; ++fm) av[fm] = *(const bf16x8*)(lds + ab + 8192 + aoff + fm*512);
    #pragma unroll
    for (int fn = 0; fn < 4; ++fn) bv[fn] = *(const bf16x8*)(lds + ab + 8192 + boff + fn*512);
    if (pre) STAGE(nxt, kt+1, 1, 0);
    __builtin_amdgcn_s_setprio(1);
    #pragma unroll
    for (int fm = 0; fm < 4; ++fm)
      #pragma unroll
      for (int fn = 0; fn < 4; ++fn)
        acc[fm][fn] = __builtin_amdgcn_mfma_f32_16x16x32_bf16(av[fm], bv[fn], acc[fm][fn], 0, 0, 0);
    __builtin_amdgcn_s_setprio(0);

    // ---- phase 4: kh1, fm 4-7 ----
    #pragma unroll
    for (int fm = 0; fm < 4; ++fm) av[fm] = *(const bf16x8*)(lds + ab + 8192 + aoff + (fm+4)*512);
    if (pre) STAGE(nxt, kt+1, 1, 1);
    __builtin_amdgcn_s_setprio(1);
    #pragma unroll
    for (int fm = 0; fm < 4; ++fm)
      #pragma unroll
      for (int fn = 0; fn < 4; ++fn)
        acc[fm+4][fn] = __builtin_amdgcn_mfma_f32_16x16x32_bf16(av[fm], bv[fn], acc[fm+4][fn], 0, 0, 0);
    __builtin_amdgcn_s_setprio(0);
  }
  #undef STAGE

  // epilogue: C/D layout col=lane&15, row=(lane>>4)*4+j
  #pragma unroll
  for (int fn = 0; fn < 4; ++fn){
    int gc = bn*256 + wn*64 + fn*16 + l15;
    float bvs = bias[gc];
    #pragma unroll
    for (int fm = 0; fm < 8; ++fm){
      size_t grow = (size_t)bm*256 + wm*128 + fm*16 + lhi*4;
      #pragma unroll
      for (int j = 0; j < 4; ++j)
        Z[(grow + j)*(size_t)HID + gc] = f2bf(acc[fm][fn][j] + bvs);
    }
  }
}

// ---------------- top-k: in-register exact 16-bit-key binary search ----------------
__global__ __launch_bounds__(256) void k_topk(const u16* __restrict__ Z,
                                              int* __restrict__ cand,
                                              int* __restrict__ cnt_out){
  __shared__ int part[4];
  __shared__ int s_cnt;
  int row = blockIdx.x, t = threadIdx.x, lane = t & 63, w = t >> 6;
  const uint4* zr = (const uint4*)(Z + (size_t)row*HID);
  uint4 kv[8];
  #pragma unroll
  for (int j = 0; j < 8; ++j){
    uint4 v = zr[t + 256*j];
    kv[j].x = key2(v.x); kv[j].y = key2(v.y); kv[j].z = key2(v.z); kv[j].w = key2(v.w);
  }
  if (t == 0) s_cnt = 0;
  __syncthreads();
  u32 lo = 0, hi = 65536;   // invariant: count(>=lo) >= 64 > count(>=hi)
  for (int it = 0; it < 16; ++it){
    u32 mid = (lo + hi) >> 1;
    int cnt = 0;
    #pragma unroll
    for (int j = 0; j < 8; ++j){
      uint4 v = kv[j];
      cnt += ((v.x & 0xFFFFu) >= mid) + ((v.x>>16) >= mid)
           + ((v.y & 0xFFFFu) >= mid) + ((v.y>>16) >= mid)
           + ((v.z & 0xFFFFu) >= mid) + ((v.z>>16) >= mid)
           + ((v.w & 0xFFFFu) >= mid) + ((v.w>>16) >= mid);
    }
    #pragma unroll
    for (int off = 32; off; off >>= 1) cnt += __shfl_down(cnt, off);
    if (lane == 0) part[w] = cnt;
    __syncthreads();
    int tot = part[0] + part[1] + part[2] + part[3];
    if (tot >= KSEL) lo = mid; else hi = mid;
    __syncthreads();
  }
  // lo = exact key of the 64th-largest bf16 z. Candidate threshold = that value - MARGIN.
  u16 k64u = (lo & 0x8000u) ? (u16)(lo ^ 0x8000u) : (u16)(~lo);
  u32 ktc = fkey(bf2f(k64u) - MARGIN);
  #pragma unroll
  for (int j = 0; j < 8; ++j){
    int ci = t + 256*j;
    uint4 v = kv[j];
    u32 hw[8] = { v.x & 0xFFFFu, v.x>>16, v.y & 0xFFFFu, v.y>>16,
                  v.z & 0xFFFFu, v.z>>16, v.w & 0xFFFFu, v.w>>16 };
    #pragma unroll
    for (int e = 0; e < 8; ++e){
      if (hw[e] >= ktc){
        int pos = atomicAdd(&s_cnt, 1);
        if (pos < CANDCAP) cand[(size_t)row*CANDCAP + pos] = ci*8 + e;
      }
    }
  }
  __syncthreads();
  if (t == 0) cnt_out[row] = s_cnt < CANDCAP ? s_cnt : CANDCAP;
}

// ---------------- fp64 refinement + exact top-64 ----------------
__global__ __launch_bounds__(256) void k_refine(const float* __restrict__ x,
                                                const float* __restrict__ mean,
                                                const float* __restrict__ encw,
                                                const float* __restrict__ encb,
                                                const int* __restrict__ cand,
                                                const int* __restrict__ cnt_in,
                                                int* __restrict__ tki,
                                                float* __restrict__ tkv){
  __shared__ float xc[D_IN];
  __shared__ double vals[CANDCAP];
  __shared__ int idxs[CANDCAP];
  int row = blockIdx.x, t = threadIdx.x, lane = t & 63, w = t >> 6;
  const float* xr = x + (size_t)row*D_IN;
  for (int i = t; i < D_IN; i += 256) xc[i] = xr[i] - mean[i];
  int cnt = cnt_in[row];
  for (int i = t; i < cnt; i += 256) idxs[i] = cand[(size_t)row*CANDCAP + i];
  __syncthreads();
  for (int cidx = w; cidx < cnt; cidx += 4){
    int h = idxs[cidx];
    const float* wr = encw + (size_t)h*D_IN;
    double s = 0.0;
    #pragma unroll 8
    for (int e = 0; e < 32; ++e){
      int d = lane + 64*e;
      s = fma((double)xc[d], (double)wr[d], s);
    }
    #pragma unroll
    for (int off = 32; off; off >>= 1) s += __shfl_down(s, off);
    if (lane == 0) vals[cidx] = s + (double)encb[h];
  }
  __syncthreads();
  for (int i = t; i < cnt; i += 256){
    double v = vals[i]; int h = idxs[i];
    int rank = 0;
    for (int j = 0; j < cnt; ++j){
      double vj = vals[j];
      rank += (vj > v) || (vj == v && idxs[j] < h);
    }
    if (rank < KSEL){ tki[(size_t)row*KSEL + rank] = h; tkv[(size_t)row*KSEL + rank] = (float)v; }
  }
}

// ---------------- dec_w transpose [2048,16384] fp32 -> [16384,2048] bf16 ----------------
__global__ __launch_bounds__(256) void k_transpose(const float* __restrict__ src,
                                                   u16* __restrict__ dst){
  __shared__ u16 tile[32][33];
  int tx = threadIdx.x & 31, ty = threadIdx.x >> 5;
  int bh = blockIdx.x;  // 0..511
  int bd = blockIdx.y;  // 0..63
  #pragma unroll
  for (int i = 0; i < 4; ++i){
    int d = bd*32 + ty + i*8;
    tile[ty + i*8][tx] = f2bf(src[(size_t)d*HID + bh*32 + tx]);
  }
  __syncthreads();
  #pragma unroll
  for (int i = 0; i < 4; ++i){
    int h = bh*32 + ty + i*8;
    dst[(size_t)h*D_IN + bd*32 + tx] = tile[tx][ty + i*8];
  }
}

// ---------------- sparse decode (bf16 weights): out = sum_k v_k * wT[h_k,:] + dec_b + mean ----
__global__ __launch_bounds__(256) void k_decode(const u16* __restrict__ wT,
                                                const int* __restrict__ tki,
                                                const float* __restrict__ tkv,
                                                const float* __restrict__ decb,
                                                const float* __restrict__ mean,
                                                float* __restrict__ out){
  __shared__ int hk[KSEL];
  __shared__ float vk[KSEL];
  int n = blockIdx.x, t = threadIdx.x;
  if (t < KSEL){ hk[t] = tki[(size_t)n*KSEL + t]; vk[t] = tkv[(size_t)n*KSEL + t]; }
  __syncthreads();
  int d0 = t*8;
  float a[8] = {0,0,0,0,0,0,0,0};
  for (int k = 0; k < KSEL; ++k){
    const u16* wr = wT + (size_t)hk[k]*D_IN + d0;
    bf16x8 wv = *(const bf16x8*)wr;
    float v = vk[k];
    #pragma unroll
    for (int j = 0; j < 8; ++j)
      a[j] = fmaf(v, bf2f((u16)wv[j]), a[j]);
  }
  float4 b0 = *(const float4*)(decb+d0);
  float4 b1 = *(const float4*)(decb+d0+4);
  float4 m0 = *(const float4*)(mean+d0);
  float4 m1 = *(const float4*)(mean+d0+4);
  float4 o0 = { a[0]+b0.x+m0.x, a[1]+b0.y+m0.y, a[2]+b0.z+m0.z, a[3]+b0.w+m0.w };
  float4 o1 = { a[4]+b1.x+m1.x, a[5]+b1.y+m1.y, a[6]+b1.z+m1.z, a[7]+b1.w+m1.w };
  *(float4*)(out + (size_t)n*D_IN + d0)     = o0;
  *(float4*)(out + (size_t)n*D_IN + d0 + 4) = o1;
}

// ---------------- workspace layout (bytes) ----------------
#define OFF_XB   ((size_t)0)                       // 33,554,432  x bf16
#define OFF_WB   ((size_t)33554432)                // 67,108,864  enc_w bf16
#define OFF_CAND ((size_t)100663296)               // 16,777,216  cand idx
#define OFF_CCNT ((size_t)117440512)               // 32,768
#define OFF_TKI  ((size_t)117473280)               // 2,097,152
#define OFF_TKV  ((size_t)119570432)               // 2,097,152
#define OFF_Z    ((size_t)121667584)               // 268,435,456 z bf16
#define OFF_WT   OFF_Z                             // 67,108,864  dec_wT bf16 (reuses z after topk)

extern "C" void kernel_launch(void* const* d_in, const int* in_sizes, int n_in,
                              void* d_out, int out_size, void* d_ws, size_t ws_size,
                              hipStream_t stream) {
  const float* x     = (const float*)d_in[0];
  const float* enc_w = (const float*)d_in[1];
  const float* enc_b = (const float*)d_in[2];
  const float* dec_w = (const float*)d_in[3];
  const float* dec_b = (const float*)d_in[4];
  const float* mean  = (const float*)d_in[5];
  float* out = (float*)d_out;
  char* ws = (char*)d_ws;

  u16* xb    = (u16*)(ws + OFF_XB);
  u16* wb    = (u16*)(ws + OFF_WB);
  int* cand  = (int*)(ws + OFF_CAND);
  int* ccnt  = (int*)(ws + OFF_CCNT);
  int* tki   = (int*)(ws + OFF_TKI);
  float* tkv = (float*)(ws + OFF_TKV);
  u16* z     = (u16*)(ws + OFF_Z);
  u16* wT    = (u16*)(ws + OFF_WT);

  k_convert_x<<<NTOK*D_IN/8/256, 256, 0, stream>>>(x, mean, xb);
  k_convert_w<<<(size_t)HID*D_IN/8/256, 256, 0, stream>>>(enc_w, wb);
  k_gemm<<<(NTOK/256)*(HID/256), 512, 0, stream>>>(xb, wb, enc_b, z);
  k_topk<<<NTOK, 256, 0, stream>>>(z, cand, ccnt);
  k_refine<<<NTOK, 256, 0, stream>>>(x, mean, enc_w, enc_b, cand, ccnt, tki, tkv);
  k_transpose<<<dim3(HID/32, D_IN/32), 256, 0, stream>>>(dec_w, wT);
  k_decode<<<NTOK, 256, 0, stream>>>(wT, tki, tkv, dec_b, mean, out);
}

// Round 3
// 1214.088 us; speedup vs baseline: 2.1314x; 1.4846x over previous
//
#include <hip/hip_runtime.h>
#include <stdint.h>

#define D_IN 2048
#define HID  16384
#define NTOK 8192
#define KSEL 64
#define CANDCAP 192
#define EPSB 0.008f

typedef __attribute__((ext_vector_type(8))) short bf16x8;
typedef __attribute__((ext_vector_type(4))) float f32x4;
typedef unsigned int u32;
typedef unsigned short u16;

__device__ __forceinline__ u16 f2bf(float f){
  u32 b = __builtin_bit_cast(u32, f);
  return (u16)((b + 0x7FFFu + ((b>>16)&1u)) >> 16);
}
__device__ __forceinline__ float bf2f(u16 u){
  return __builtin_bit_cast(float, (u32)u << 16);
}
__device__ __forceinline__ u16 f2h(float f){
  return __builtin_bit_cast(u16, (_Float16)f);
}
__device__ __forceinline__ float h2f(u16 u){
  return (float)__builtin_bit_cast(_Float16, u);
}
// monotone order-key for IEEE sign-magnitude 16-bit patterns
__device__ __forceinline__ u16 key_of(u16 u){
  return (u & 0x8000u) ? (u16)(~u) : (u16)(u | 0x8000u);
}
__device__ __forceinline__ u16 kinv(u32 k){
  return (k & 0x8000u) ? (u16)(k & 0x7FFFu) : (u16)(~k);
}
__device__ __forceinline__ u32 fkey16(float f){ return (u32)key_of(f2h(f)); }
__device__ __forceinline__ u32 key2(u32 p){
  u32 lo = p & 0xFFFFu, hi = p >> 16;
  lo = (lo & 0x8000u) ? ((~lo)&0xFFFFu) : (lo|0x8000u);
  hi = (hi & 0x8000u) ? ((~hi)&0xFFFFu) : (hi|0x8000u);
  return lo | (hi<<16);
}

// ---------------- convert: x-mean -> bf16, enc_w -> bf16 ----------------
__global__ __launch_bounds__(256) void k_convert_x(const float* __restrict__ x,
                                                   const float* __restrict__ mean,
                                                   u16* __restrict__ xb){
  long i = (long)blockIdx.x*256 + threadIdx.x;
  long base = i*8;
  int d = (int)(base & (D_IN-1));
  float4 a = *(const float4*)(x+base);
  float4 b = *(const float4*)(x+base+4);
  float4 m0 = *(const float4*)(mean+d);
  float4 m1 = *(const float4*)(mean+d+4);
  uint4 ov;
  ov.x = (u32)f2bf(a.x-m0.x) | ((u32)f2bf(a.y-m0.y)<<16);
  ov.y = (u32)f2bf(a.z-m0.z) | ((u32)f2bf(a.w-m0.w)<<16);
  ov.z = (u32)f2bf(b.x-m1.x) | ((u32)f2bf(b.y-m1.y)<<16);
  ov.w = (u32)f2bf(b.z-m1.z) | ((u32)f2bf(b.w-m1.w)<<16);
  *(uint4*)(xb+base) = ov;
}

__global__ __launch_bounds__(256) void k_convert_w(const float* __restrict__ wsrc,
                                                   u16* __restrict__ wb){
  long i = (long)blockIdx.x*256 + threadIdx.x;
  long base = i*8;
  float4 a = *(const float4*)(wsrc+base);
  float4 b = *(const float4*)(wsrc+base+4);
  uint4 ov;
  ov.x = (u32)f2bf(a.x) | ((u32)f2bf(a.y)<<16);
  ov.y = (u32)f2bf(a.z) | ((u32)f2bf(a.w)<<16);
  ov.z = (u32)f2bf(b.x) | ((u32)f2bf(b.y)<<16);
  ov.w = (u32)f2bf(b.z) | ((u32)f2bf(b.w)<<16);
  *(uint4*)(wb+base) = ov;
}

// ---------------- bf16 GEMM, 256x256 tile, BK=64, 8 waves, phase-split counted-vmcnt ----
__global__ __launch_bounds__(512, 2) void k_gemm(const u16* __restrict__ A,   // [NTOK, D_IN]
                                                 const u16* __restrict__ B,   // [HID, D_IN]
                                                 const float* __restrict__ bias,
                                                 u16* __restrict__ Z){        // [NTOK, HID] fp16
  __shared__ u16 lds[65536];   // 128 KiB
  const int t = threadIdx.x, lane = t & 63, w = t >> 6;
  const int wm = w >> 2, wn = w & 3;
  const int l15 = lane & 15, lhi = lane >> 4;

  int wg = blockIdx.x;
  int wgid = (wg & 7)*256 + (wg >> 3);
  int sb = wgid >> 6, wi = wgid & 63;
  int bm = (sb & 3)*8 + (wi & 7);      // 0..31
  int bn = (sb >> 2)*8 + (wi >> 3);    // 0..63
  const u16* aT = A + (size_t)bm*256*D_IN;
  const u16* bT = B + (size_t)bn*256*D_IN;

  int srcOff[2], ldst[2];
  #pragma unroll
  for (int i = 0; i < 2; ++i){
    int sr = i*64 + w*8 + (lane >> 3);
    int u  = (lane & 7) ^ (sr & 7);
    int r  = (sr << 1) | (u >> 2);
    int c8 = (u & 3) * 8;
    srcOff[i] = r*D_IN + c8;
    ldst[i]   = i*4096 + w*512 + lane*8;
  }
  #define STAGE(bufb, ktp, khh, isB) do { \
    const u16* _s = ((isB) ? bT : aT) + (ktp)*64 + (khh)*32; \
    u16* _d = lds + (bufb)*32768 + ((isB)?16384:0) + (khh)*8192; \
    __builtin_amdgcn_global_load_lds( \
      (const __attribute__((address_space(1))) u32*)(_s + srcOff[0]), \
      (__attribute__((address_space(3))) u32*)(_d + ldst[0]), 16, 0, 0); \
    __builtin_amdgcn_global_load_lds( \
      (const __attribute__((address_space(1))) u32*)(_s + srcOff[1]), \
      (__attribute__((address_space(3))) u32*)(_d + ldst[1]), 16, 0, 0); \
  } while(0)

  const int slot = ((((l15 & 1) << 2) | lhi) ^ (l15 >> 1)) * 8;
  const int aoff = (wm*64 + (l15 >> 1))*64 + slot;
  const int boff = (wn*32 + (l15 >> 1))*64 + slot + 16384;

  f32x4 acc[8][4] = {};

  STAGE(0, 0, 0, 0); STAGE(0, 0, 0, 1); STAGE(0, 0, 1, 0); STAGE(0, 0, 1, 1);

  #pragma unroll 1
  for (int kt = 0; kt < D_IN/64; ++kt){
    const int cur = kt & 1, nxt = cur ^ 1;
    const int ab = cur*32768;
    const bool pre = (kt < D_IN/64 - 1);
    bf16x8 av[4], bv[4];

    asm volatile("s_waitcnt vmcnt(4)" ::: "memory");
    __builtin_amdgcn_s_barrier();
    #pragma unroll
    for (int fm = 0; fm < 4; ++fm) av[fm] = *(const bf16x8*)(lds + ab + aoff + fm*512);
    #pragma unroll
    for (int fn = 0; fn < 4; ++fn) bv[fn] = *(const bf16x8*)(lds + ab + boff + fn*512);
    if (pre) STAGE(nxt, kt+1, 0, 0);
    __builtin_amdgcn_s_setprio(1);
    #pragma unroll
    for (int fm = 0; fm < 4; ++fm)
      #pragma unroll
      for (int fn = 0; fn < 4; ++fn)
        acc[fm][fn] = __builtin_amdgcn_mfma_f32_16x16x32_bf16(av[fm], bv[fn], acc[fm][fn], 0, 0, 0);
    __builtin_amdgcn_s_setprio(0);

    #pragma unroll
    for (int fm = 0; fm < 4; ++fm) av[fm] = *(const bf16x8*)(lds + ab + aoff + (fm+4)*512);
    if (pre) STAGE(nxt, kt+1, 0, 1);
    __builtin_amdgcn_s_setprio(1);
    #pragma unroll
    for (int fm = 0; fm < 4; ++fm)
      #pragma unroll
      for (int fn = 0; fn < 4; ++fn)
        acc[fm+4][fn] = __builtin_amdgcn_mfma_f32_16x16x32_bf16(av[fm], bv[fn], acc[fm+4][fn], 0, 0, 0);
    __builtin_amdgcn_s_setprio(0);

    if (pre) { asm volatile("s_waitcnt vmcnt(4)" ::: "memory"); }
    else     { asm volatile("s_waitcnt vmcnt(0)" ::: "memory"); }
    __builtin_amdgcn_s_barrier();
    #pragma unroll
    for (int fm = 0; fm < 4; ++fm) av[fm] = *(const bf16x8*)(lds + ab + 8192 + aoff + fm*512);
    #pragma unroll
    for (int fn = 0; fn < 4; ++fn) bv[fn] = *(const bf16x8*)(lds + ab + 8192 + boff + fn*512);
    if (pre) STAGE(nxt, kt+1, 1, 0);
    __builtin_amdgcn_s_setprio(1);
    #pragma unroll
    for (int fm = 0; fm < 4; ++fm)
      #pragma unroll
      for (int fn = 0; fn < 4; ++fn)
        acc[fm][fn] = __builtin_amdgcn_mfma_f32_16x16x32_bf16(av[fm], bv[fn], acc[fm][fn], 0, 0, 0);
    __builtin_amdgcn_s_setprio(0);

    #pragma unroll
    for (int fm = 0; fm < 4; ++fm) av[fm] = *(const bf16x8*)(lds + ab + 8192 + aoff + (fm+4)*512);
    if (pre) STAGE(nxt, kt+1, 1, 1);
    __builtin_amdgcn_s_setprio(1);
    #pragma unroll
    for (int fm = 0; fm < 4; ++fm)
      #pragma unroll
      for (int fn = 0; fn < 4; ++fn)
        acc[fm+4][fn] = __builtin_amdgcn_mfma_f32_16x16x32_bf16(av[fm], bv[fn], acc[fm+4][fn], 0, 0, 0);
    __builtin_amdgcn_s_setprio(0);
  }
  #undef STAGE

  // epilogue: C/D layout col=lane&15, row=(lane>>4)*4+j ; write fp16 z
  #pragma unroll
  for (int fn = 0; fn < 4; ++fn){
    int gc = bn*256 + wn*64 + fn*16 + l15;
    float bvs = bias[gc];
    #pragma unroll
    for (int fm = 0; fm < 8; ++fm){
      size_t grow = (size_t)bm*256 + wm*128 + fm*16 + lhi*4;
      #pragma unroll
      for (int j = 0; j < 4; ++j)
        Z[(grow + j)*(size_t)HID + gc] = f2h(acc[fm][fn][j] + bvs);
    }
  }
}

// ---------------- topk: exact fp16-key binary search + 3-way classification ----------------
// sure-in  (z >= T+2eps): write idx+value directly to tki/tkv[0..S)
// ambiguous (T-2eps <= z < T+2eps): write idx to cand list for fp64 refine
__global__ __launch_bounds__(256) void k_topk(const u16* __restrict__ Z,
                                              int* __restrict__ cand,
                                              int* __restrict__ scnt_out,
                                              int* __restrict__ acnt_out,
                                              int* __restrict__ tki,
                                              float* __restrict__ tkv){
  __shared__ int part[4];
  __shared__ int s_cnt, a_cnt;
  int row = blockIdx.x, t = threadIdx.x, lane = t & 63, w = t >> 6;
  const uint4* zr = (const uint4*)(Z + (size_t)row*HID);
  uint4 kv[8];
  #pragma unroll
  for (int j = 0; j < 8; ++j){
    uint4 v = zr[t + 256*j];
    kv[j].x = key2(v.x); kv[j].y = key2(v.y); kv[j].z = key2(v.z); kv[j].w = key2(v.w);
  }
  if (t == 0){ s_cnt = 0; a_cnt = 0; }
  __syncthreads();
  u32 lo = 0, hi = 65536;   // invariant: count(>=lo) >= 64 > count(>=hi)
  for (int it = 0; it < 16; ++it){
    u32 mid = (lo + hi) >> 1;
    int cnt = 0;
    #pragma unroll
    for (int j = 0; j < 8; ++j){
      uint4 v = kv[j];
      cnt += ((v.x & 0xFFFFu) >= mid) + ((v.x>>16) >= mid)
           + ((v.y & 0xFFFFu) >= mid) + ((v.y>>16) >= mid)
           + ((v.z & 0xFFFFu) >= mid) + ((v.z>>16) >= mid)
           + ((v.w & 0xFFFFu) >= mid) + ((v.w>>16) >= mid);
    }
    #pragma unroll
    for (int off = 32; off; off >>= 1) cnt += __shfl_down(cnt, off);
    if (lane == 0) part[w] = cnt;
    __syncthreads();
    int tot = part[0] + part[1] + part[2] + part[3];
    if (tot >= KSEL) lo = mid; else hi = mid;
    __syncthreads();
  }
  float T = h2f(kinv(lo));            // exact fp16 64th-largest of noisy z
  u32 khi = fkey16(T + 2.0f*EPSB);
  u32 klo = fkey16(T - 2.0f*EPSB);
  #pragma unroll
  for (int j = 0; j < 8; ++j){
    int ci = t + 256*j;
    uint4 v = kv[j];
    u32 hw[8] = { v.x & 0xFFFFu, v.x>>16, v.y & 0xFFFFu, v.y>>16,
                  v.z & 0xFFFFu, v.z>>16, v.w & 0xFFFFu, v.w>>16 };
    #pragma unroll
    for (int e = 0; e < 8; ++e){
      if (hw[e] >= khi){                      // surely in top-64
        int pos = atomicAdd(&s_cnt, 1);
        tki[(size_t)row*KSEL + pos] = ci*8 + e;
        tkv[(size_t)row*KSEL + pos] = h2f(kinv(hw[e]));
      } else if (hw[e] >= klo){               // ambiguous band
        int pos = atomicAdd(&a_cnt, 1);
        if (pos < CANDCAP) cand[(size_t)row*CANDCAP + pos] = ci*8 + e;
      }
    }
  }
  __syncthreads();
  if (t == 0){
    scnt_out[row] = s_cnt;
    acnt_out[row] = a_cnt < CANDCAP ? a_cnt : CANDCAP;
  }
}

// ---------------- fp64 refine of ambiguous band, fill slots [S..64) ----------------
// one wave per row; x row kept in registers (8 x float4 per lane)
__global__ __launch_bounds__(256) void k_refine(const float* __restrict__ x,
                                                const float* __restrict__ mean,
                                                const float* __restrict__ encw,
                                                const float* __restrict__ encb,
                                                const int* __restrict__ cand,
                                                const int* __restrict__ scnt_in,
                                                const int* __restrict__ acnt_in,
                                                int* __restrict__ tki,
                                                float* __restrict__ tkv){
  __shared__ double vals[4][CANDCAP];
  __shared__ int    hidx[4][CANDCAP];
  int t = threadIdx.x, lane = t & 63, w = t >> 6;
  int row = blockIdx.x*4 + w;
  const float* xr = x + (size_t)row*D_IN;
  float4 xv[8];
  #pragma unroll
  for (int e = 0; e < 8; ++e){
    float4 a = *(const float4*)(xr + (lane + 64*e)*4);
    float4 m = *(const float4*)(mean + (lane + 64*e)*4);
    xv[e].x = a.x-m.x; xv[e].y = a.y-m.y; xv[e].z = a.z-m.z; xv[e].w = a.w-m.w;
  }
  int S = scnt_in[row];
  int A = acnt_in[row];
  int need = KSEL - S;
  for (int c = 0; c < A; ++c){
    int h = cand[(size_t)row*CANDCAP + c];
    const float4* wr = (const float4*)(encw + (size_t)h*D_IN);
    double s = 0.0;
    #pragma unroll
    for (int e = 0; e < 8; ++e){
      float4 w4 = wr[lane + 64*e];
      s = fma((double)xv[e].x, (double)w4.x, s);
      s = fma((double)xv[e].y, (double)w4.y, s);
      s = fma((double)xv[e].z, (double)w4.z, s);
      s = fma((double)xv[e].w, (double)w4.w, s);
    }
    #pragma unroll
    for (int off = 32; off; off >>= 1) s += __shfl_down(s, off);
    if (lane == 0){ vals[w][c] = s + (double)encb[h]; hidx[w][c] = h; }
  }
  // rank ambiguous values (fp64 exact), keep top `need`
  for (int c = lane; c < A; c += 64){
    double v = vals[w][c]; int h = hidx[w][c];
    int rank = 0;
    for (int j = 0; j < A; ++j){
      double vj = vals[w][j];
      rank += (vj > v) || (vj == v && hidx[w][j] < h);
    }
    if (rank < need){
      tki[(size_t)row*KSEL + S + rank] = h;
      tkv[(size_t)row*KSEL + S + rank] = (float)v;
    }
  }
}

// ---------------- dec_w transpose [2048,16384] fp32 -> [16384,2048] bf16 ----------------
__global__ __launch_bounds__(256) void k_transpose(const float* __restrict__ src,
                                                   u16* __restrict__ dst){
  __shared__ u16 tile[32][33];
  int tx = threadIdx.x & 31, ty = threadIdx.x >> 5;
  int bh = blockIdx.x;
  int bd = blockIdx.y;
  #pragma unroll
  for (int i = 0; i < 4; ++i){
    int d = bd*32 + ty + i*8;
    tile[ty + i*8][tx] = f2bf(src[(size_t)d*HID + bh*32 + tx]);
  }
  __syncthreads();
  #pragma unroll
  for (int i = 0; i < 4; ++i){
    int h = bh*32 + ty + i*8;
    dst[(size_t)h*D_IN + bd*32 + tx] = tile[tx][ty + i*8];
  }
}

// ---------------- sparse decode (bf16 weights) ----------------
__global__ __launch_bounds__(256) void k_decode(const u16* __restrict__ wT,
                                                const int* __restrict__ tki,
                                                const float* __restrict__ tkv,
                                                const float* __restrict__ decb,
                                                const float* __restrict__ mean,
                                                float* __restrict__ out){
  __shared__ int hk[KSEL];
  __shared__ float vk[KSEL];
  int n = blockIdx.x, t = threadIdx.x;
  if (t < KSEL){ hk[t] = tki[(size_t)n*KSEL + t]; vk[t] = tkv[(size_t)n*KSEL + t]; }
  __syncthreads();
  int d0 = t*8;
  float a[8] = {0,0,0,0,0,0,0,0};
  for (int k = 0; k < KSEL; ++k){
    const u16* wr = wT + (size_t)hk[k]*D_IN + d0;
    bf16x8 wv = *(const bf16x8*)wr;
    float v = vk[k];
    #pragma unroll
    for (int j = 0; j < 8; ++j)
      a[j] = fmaf(v, bf2f((u16)wv[j]), a[j]);
  }
  float4 b0 = *(const float4*)(decb+d0);
  float4 b1 = *(const float4*)(decb+d0+4);
  float4 m0 = *(const float4*)(mean+d0);
  float4 m1 = *(const float4*)(mean+d0+4);
  float4 o0 = { a[0]+b0.x+m0.x, a[1]+b0.y+m0.y, a[2]+b0.z+m0.z, a[3]+b0.w+m0.w };
  float4 o1 = { a[4]+b1.x+m1.x, a[5]+b1.y+m1.y, a[6]+b1.z+m1.z, a[7]+b1.w+m1.w };
  *(float4*)(out + (size_t)n*D_IN + d0)     = o0;
  *(float4*)(out + (size_t)n*D_IN + d0 + 4) = o1;
}

// ---------------- workspace layout (bytes) ----------------
#define OFF_XB   ((size_t)0)                 // 33,554,432   x bf16
#define OFF_WB   ((size_t)33554432)          // 67,108,864   enc_w bf16
#define OFF_CAND ((size_t)100663296)         // 6,291,456    ambig idx (8192*192*4)
#define OFF_SCNT ((size_t)106954752)         // 32,768
#define OFF_ACNT ((size_t)106987520)         // 32,768
#define OFF_TKI  ((size_t)107020288)         // 2,097,152
#define OFF_TKV  ((size_t)109117440)         // 2,097,152
#define OFF_Z    ((size_t)111214592)         // 268,435,456  z fp16
#define OFF_WT   OFF_Z                       // 67,108,864   dec_wT bf16 (reuses z)

extern "C" void kernel_launch(void* const* d_in, const int* in_sizes, int n_in,
                              void* d_out, int out_size, void* d_ws, size_t ws_size,
                              hipStream_t stream) {
  const float* x     = (const float*)d_in[0];
  const float* enc_w = (const float*)d_in[1];
  const float* enc_b = (const float*)d_in[2];
  const float* dec_w = (const float*)d_in[3];
  const float* dec_b = (const float*)d_in[4];
  const float* mean  = (const float*)d_in[5];
  float* out = (float*)d_out;
  char* ws = (char*)d_ws;

  u16* xb    = (u16*)(ws + OFF_XB);
  u16* wb    = (u16*)(ws + OFF_WB);
  int* cand  = (int*)(ws + OFF_CAND);
  int* scnt  = (int*)(ws + OFF_SCNT);
  int* acnt  = (int*)(ws + OFF_ACNT);
  int* tki   = (int*)(ws + OFF_TKI);
  float* tkv = (float*)(ws + OFF_TKV);
  u16* z     = (u16*)(ws + OFF_Z);
  u16* wT    = (u16*)(ws + OFF_WT);

  k_convert_x<<<NTOK*D_IN/8/256, 256, 0, stream>>>(x, mean, xb);
  k_convert_w<<<(size_t)HID*D_IN/8/256, 256, 0, stream>>>(enc_w, wb);
  k_gemm<<<(NTOK/256)*(HID/256), 512, 0, stream>>>(xb, wb, enc_b, z);
  k_topk<<<NTOK, 256, 0, stream>>>(z, cand, scnt, acnt, tki, tkv);
  k_refine<<<NTOK/4, 256, 0, stream>>>(x, mean, enc_w, enc_b, cand, scnt, acnt, tki, tkv);
  k_transpose<<<dim3(HID/32, D_IN/32), 256, 0, stream>>>(dec_w, wT);
  k_decode<<<NTOK, 256, 0, stream>>>(wT, tki, tkv, dec_b, mean, out);
}